// Round 6
// baseline (336.596 us; speedup 1.0000x reference)
//
#include <hip/hip_runtime.h>
#include <math.h>

namespace {

constexpr int H = 2048;
constexpr int W = 2048;
constexpr int CPT = 4;                           // cells per thread
constexpr float TANH_C  = 1.1486328125f;
constexpr float DEG2RAD = 0.017453292519943295f; // == np.float32(pi/180)
constexpr float RT2H    = 0.70710678118654752f;  // sqrt(2)/2
constexpr float BAND    = 2.5e-4f;               // fast-path err ~4e-5 << BAND

// out layout: [0,HW) p_ignite, [HW,2HW) new_burning (0/1), [2HW,3HW) new_burned
__global__ __launch_bounds__(256) void wildfire_step(
    const float* __restrict__ p_veg,  const float* __restrict__ p_den,
    const float* __restrict__ wind_v, const float* __restrict__ wind_d,
    const float* __restrict__ slope,
    const float* __restrict__ s_a,  const float* __restrict__ s_ph,
    const float* __restrict__ s_c1, const float* __restrict__ s_c2,
    const float* __restrict__ s_pc,
    const float* __restrict__ rand_ig, const float* __restrict__ rand_co,
    const int* __restrict__ burning, const int* __restrict__ burned,
    float* __restrict__ out)
{
    // burning halo: rows i-1..i+1, LDS col c maps grid col j0-4+c; main cells at c=4..1027
    __shared__ float sb[3][1032];
    const int t    = (int)threadIdx.x;
    const int i    = (int)blockIdx.y;
    const int j0   = (int)blockIdx.x * (256 * CPT);   // 1024-wide tile
    const int idx0 = i * W + j0 + CPT * t;            // first of this thread's 4 cells

    // ---------- all global loads, 16 B/lane ----------
    const float4 pv4  = *(const float4*)(p_veg  + idx0);
    const float4 pd4  = *(const float4*)(p_den  + idx0);
    const float4 wv4  = *(const float4*)(wind_v + idx0);
    const float4 wd4  = *(const float4*)(wind_d + idx0);
    const float4 rig4 = *(const float4*)(rand_ig + idx0);
    const float4 rco4 = *(const float4*)(rand_co + idx0);
    const int4   bd4  = *(const int4*)  (burned + idx0);

    float4 sl4[9];                                    // 4 cells x 9 floats, contiguous
    {
        const float4* sg = (const float4*)(slope + (size_t)idx0 * 9);
        #pragma unroll
        for (int k = 0; k < 9; ++k) sl4[k] = sg[k];
    }
    const float* sl = (const float*)sl4;              // sl[9*u + si], const-indexed after unroll

    // burning halo rows via int4
    #pragma unroll
    for (int r = 0; r < 3; ++r) {
        const int ii = i - 1 + r;
        int4 b4 = make_int4(0, 0, 0, 0);
        if (ii >= 0 && ii < H)
            b4 = *(const int4*)(burning + (size_t)ii * W + j0 + CPT * t);
        float4 f;
        f.x = b4.x ? 1.f : 0.f; f.y = b4.y ? 1.f : 0.f;
        f.z = b4.z ? 1.f : 0.f; f.w = b4.w ? 1.f : 0.f;
        *(float4*)&sb[r][4 + CPT * t] = f;
    }
    if (t < 6) {                                      // edge cols j0-1 and j0+1024
        const int r  = t >> 1, side = t & 1;
        const int ii = i - 1 + r;
        const int jj = side ? (j0 + 1024) : (j0 - 1);
        float v = 0.f;
        if (ii >= 0 && ii < H && jj >= 0 && jj < W)
            v = burning[(size_t)ii * W + jj] ? 1.f : 0.f;
        sb[r][side ? 1028 : 3] = v;
    }

    const float a      = s_a[0];
    const float p_h    = s_ph[0];
    const float c1     = s_c1[0];
    const float c2     = s_c2[0];
    const float p_cont = s_pc[0];
    const float asl    = a * DEG2RAD;

    __syncthreads();

    const float pvv[4] = {pv4.x, pv4.y, pv4.z, pv4.w};
    const float pdv[4] = {pd4.x, pd4.y, pd4.z, pd4.w};
    const float wvv[4] = {wv4.x, wv4.y, wv4.z, wv4.w};
    const float wdv[4] = {wd4.x, wd4.y, wd4.z, wd4.w};
    const float rgv[4] = {rig4.x, rig4.y, rig4.z, rig4.w};
    const float rcv[4] = {rco4.x, rco4.y, rco4.z, rco4.w};
    const int   bdv[4] = {bd4.x, bd4.y, bd4.z, bd4.w};

    float pig[4], nbo[4], ndo[4];

    #pragma unroll
    for (int u = 0; u < CPT; ++u) {
        const int c = 4 + CPT * t + u;                // LDS col of this cell
        const float b0 = sb[0][c-1], b1 = sb[0][c], b2 = sb[0][c+1];
        const float b3 = sb[1][c-1], bc = sb[1][c], b5 = sb[1][c+1];
        const float b6 = sb[2][c-1], b7 = sb[2][c], b8 = sb[2][c+1];

        const bool  is_burning = (bc != 0.f);
        const float any_n = b0 + b1 + b2 + b3 + b5 + b6 + b7 + b8; // integer-valued

        float p_ig   = 0.f;
        bool  new_ig = false;

        if (__any(any_n != 0.f)) {
            const float wd  = wdv[u];
            const float wv  = wvv[u];
            const float wr  = wd * DEG2RAD;
            const float cw  = __cosf(wr);
            const float sw  = __sinf(wr);
            const float ew  = __expf(c1 * wv);
            const float cvw = c2 * wv;
            const float p_base = (p_h * (1.f + pvv[u])) * (1.f + pdv[u]);
            const float Cz2 = 2.f * (TANH_C * (p_base * ew));

            // 1 - tanh(z_k)*b_k = b_k ? 2/(E_k+1) : 1,  E_k = exp(Cz2*exp(u_k))
            // => p_ignite = 1 - 2^m / prod(fma(b_k, E_k, 1))
#define NB(K, b, CK, SK, si)                                                   \
            const float ct##K = fmaf(cw, (CK), sw * (SK));                     \
            const float eu##K = __expf(fmaf(cvw, ct##K - 1.f, asl * sl[9*u + si])); \
            const float E##K  = __expf(Cz2 * eu##K);                           \
            const float d##K  = fmaf((b), E##K, 1.f);

            NB(0, b0,  RT2H, -RT2H, 0)   // 315
            NB(1, b1,  0.f,  -1.f,  1)   // 270
            NB(2, b2, -RT2H, -RT2H, 2)   // 225
            NB(3, b3,  1.f,   0.f,  3)   //   0
            NB(5, b5, -1.f,   0.f,  5)   // 180
            NB(6, b6,  RT2H,  RT2H, 6)   //  45
            NB(7, b7,  0.f,   1.f,  7)   //  90
            NB(8, b8, -RT2H,  RT2H, 8)   // 135
#undef NB
            const float den = ((d0 * d1) * (d2 * d3)) * ((d5 * d6) * (d7 * d8));
            const float num = (float)(1 << (int)any_n);   // 2^m exact
            p_ig = 1.f - num * __builtin_amdgcn_rcpf(den);

            new_ig = (!is_burning) && (bdv[u] == 0) && (rgv[u] < p_ig);

            // precise recheck where the bool could flip (~60 cells / grid)
            const bool need = (any_n != 0.f) && (fabsf(rgv[u] - p_ig) < BAND);
            if (__any((int)need)) {
                if (need) {
                    const float ewp = expf(c1 * wv);
                    float prod = 1.f;
#define NBP(b, dirdeg, si)                                                     \
                    if ((b) != 0.f) {                                          \
                        const float th = (wd - (dirdeg)) * DEG2RAD;            \
                        const float pw = ewp * expf(cvw * (cosf(th) - 1.f));   \
                        const float ps = expf((a * sl[9*u + si]) * DEG2RAD);   \
                        const float pp = tanhf(TANH_C * ((p_base * pw) * ps)); \
                        prod *= 1.f - pp * (b);                                \
                    }
                    NBP(b0, 315.f, 0)
                    NBP(b1, 270.f, 1)
                    NBP(b2, 225.f, 2)
                    NBP(b3,   0.f, 3)
                    NBP(b5, 180.f, 5)
                    NBP(b6,  45.f, 6)
                    NBP(b7,  90.f, 7)
                    NBP(b8, 135.f, 8)
#undef NBP
                    p_ig   = 1.f - prod;
                    new_ig = (!is_burning) && (bdv[u] == 0) && (rgv[u] < p_ig);
                }
            }
        }

        const bool keep = is_burning && (rcv[u] < p_cont);
        pig[u] = p_ig;
        nbo[u] = (new_ig || keep) ? 1.f : 0.f;
        ndo[u] = ((bdv[u] != 0) || (is_burning && !keep)) ? 1.f : 0.f;
    }

    // ---------- 16 B/lane stores ----------
    *(float4*)(out + idx0)             = make_float4(pig[0], pig[1], pig[2], pig[3]);
    *(float4*)(out + H * W + idx0)     = make_float4(nbo[0], nbo[1], nbo[2], nbo[3]);
    *(float4*)(out + 2 * H * W + idx0) = make_float4(ndo[0], ndo[1], ndo[2], ndo[3]);
}

} // namespace

extern "C" void kernel_launch(void* const* d_in, const int* in_sizes, int n_in,
                              void* d_out, int out_size, void* d_ws, size_t ws_size,
                              hipStream_t stream)
{
    (void)in_sizes; (void)n_in; (void)out_size; (void)d_ws; (void)ws_size;
    dim3 grid(W / (256 * CPT), H, 1);
    dim3 block(256, 1, 1);
    hipLaunchKernelGGL(wildfire_step, grid, block, 0, stream,
        (const float*)d_in[0],  (const float*)d_in[1],
        (const float*)d_in[2],  (const float*)d_in[3],
        (const float*)d_in[4],
        (const float*)d_in[5],  (const float*)d_in[6],
        (const float*)d_in[7],  (const float*)d_in[8],
        (const float*)d_in[9],
        (const float*)d_in[10], (const float*)d_in[11],
        (const int*)d_in[12],   (const int*)d_in[13],
        (float*)d_out);
}